// Round 4
// baseline (867.077 us; speedup 1.0000x reference)
//
#include <hip/hip_runtime.h>
#include <math.h>

typedef __attribute__((ext_vector_type(8))) short short8;
typedef __attribute__((ext_vector_type(4))) short shortx4;
typedef __attribute__((ext_vector_type(4))) int   intx4;
typedef __attribute__((ext_vector_type(4))) float floatx4;

#define BQ 256
#define SQ 256
#define DQ 256
#define HQ 4
#define DHQ 64

__device__ __forceinline__ short f2bf(float f) {
  union { float f; unsigned u; } c; c.f = f;
  unsigned r = c.u + 0x7fffu + ((c.u >> 16) & 1u);
  return (short)(r >> 16);
}
__device__ __forceinline__ float bf2f(short s) {
  union { unsigned u; float f; } c; c.u = ((unsigned)(unsigned short)s) << 16;
  return c.f;
}
__device__ __forceinline__ float gelu_fast(float x) {
  float t = x * (0.7978845608f + 0.0356774081f * x * x);
  return x / (1.0f + __expf(-2.0f * t));
}

__device__ __forceinline__ void async16(const void* g, void* l) {
  __builtin_amdgcn_global_load_lds(
      (const __attribute__((address_space(1))) void*)g,
      (__attribute__((address_space(3))) void*)l, 16, 0, 0);
}

// ---------------- weight convert + transpose: W[L,K,N] f32 -> Wt[L,N,K] bf16 --------
__global__ __launch_bounds__(256) void wconv_kernel(const float* __restrict__ W,
    short* __restrict__ Wt, int K, int N, int total) {
  int idx = blockIdx.x * 256 + threadIdx.x;
  if (idx >= total) return;
  int nk = N * K;
  int l = idx / nk;
  int r = idx - l * nk;
  int n = r / K;
  int k = r - n * K;
  Wt[idx] = f2bf(W[(size_t)l * nk + (size_t)k * N + n]);
}

// ---------------- merged QKV weight convert: -> [L][3][256][256] (N,K) --------------
__global__ __launch_bounds__(256) void wconv_qkv_kernel(const float* __restrict__ Wq,
    const float* __restrict__ Wk, const float* __restrict__ Wv, short* __restrict__ Wt) {
  int idx = blockIdx.x * 256 + threadIdx.x;     // 0 .. 393215
  int l = idx / 196608;
  int r = idx - l * 196608;
  int which = r / 65536;
  int e = r & 65535;
  int n = e >> 8, k = e & 255;
  const float* W = (which == 0) ? Wq : ((which == 1) ? Wk : Wv);
  Wt[idx] = f2bf(W[l * 65536 + k * 256 + n]);
}

// ---------------- concat q/k/v biases: dst[l][768] ----------------------------------
__global__ __launch_bounds__(256) void bconv_kernel(const float* __restrict__ bq,
    const float* __restrict__ bk, const float* __restrict__ bv, float* __restrict__ dst) {
  int i = blockIdx.x * 256 + threadIdx.x;
  int l = i / 768, r = i - l * 768;
  const float* src = (r < 256) ? bq : ((r < 512) ? bk : bv);
  dst[i] = src[l * 256 + (r & 255)];
}

// ---------------- embedding + LN; writes xb (bf16) and total (f32) ------------------
__global__ __launch_bounds__(256) void embed_kernel(const int* __restrict__ ids,
    const float* __restrict__ item, const float* __restrict__ pos,
    short* __restrict__ xb, float* __restrict__ tot) {
  const int tid = threadIdx.x, lane = tid & 63, w = tid >> 6;
  const int row = blockIdx.x * 4 + w;
  const int s = row & (SQ - 1);
  const int id = ids[row];
  floatx4 a = *(const floatx4*)(item + (size_t)id * DQ + lane * 4);
  floatx4 p = *(const floatx4*)(pos + (size_t)s * DQ + lane * 4);
  float v[4];
#pragma unroll
  for (int i = 0; i < 4; ++i) v[i] = a[i] + p[i];
  float sm = v[0] + v[1] + v[2] + v[3];
  float ss = v[0]*v[0] + v[1]*v[1] + v[2]*v[2] + v[3]*v[3];
#pragma unroll
  for (int off = 32; off; off >>= 1) { sm += __shfl_xor(sm, off); ss += __shfl_xor(ss, off); }
  float mu = sm * (1.0f / DQ);
  float var = ss * (1.0f / DQ) - mu * mu;
  float rs = rsqrtf(var + 1e-5f);
  shortx4 o; floatx4 y;
#pragma unroll
  for (int i = 0; i < 4; ++i) { y[i] = (v[i] - mu) * rs; o[i] = f2bf(y[i]); }
  *(shortx4*)(xb + (size_t)row * DQ + lane * 4) = o;
  *(floatx4*)(tot + (size_t)row * DQ + lane * 4) = y;
}

// ---------------- bf16 MFMA GEMM, tile 128x256, 512 threads, swizzled LDS -----------
// out[M,N] = A[M,K] @ Bt[N,K]^T + bias ; optional res-add, gelu, row-LN, tot += y
// chunked: out chunk bn at out + bn*M*256 ; vt: bn==2 chunk stored transposed to vt.
__global__ __launch_bounds__(512, 4) void gemm_kernel(
    const short* __restrict__ A, const short* __restrict__ Bt,
    const float* __restrict__ bias, const short* __restrict__ res,
    short* __restrict__ out, float* __restrict__ tot, short* __restrict__ vt,
    int M, int N, int K, int act, int ln, int chunked) {
  __shared__ short smem[12288];            // As 4096 | Bs 8192 ; epilogue reuse
  short* As = smem;
  short* Bs = smem + 4096;
  float* redS  = (float*)(smem + 8448);    // [128][4]
  float* redS2 = redS + 512;
  const int tid = threadIdx.x, lane = tid & 63, w = tid >> 6;
  const int lane15 = lane & 15, quad = lane >> 4;
  const int wm = w & 1, wn = w >> 1;
  const int bm = blockIdx.y, bn = blockIdx.x;

  // staging: LDS layout linear (forced by global_load_lds); swizzle realized by
  // permuting the GLOBAL 16B-group each lane fetches: group = (lane&3) ^ swz(row)
  const int rA = lane >> 2;                              // row within 16-row chunk
  const int swzA = (rA & 3) ^ ((rA >> 2) & 3);
  const int gA = ((lane & 3) ^ swzA) * 8;
  const short* Ag  = A  + (size_t)(bm * 128 + w * 16 + rA) * K + gA;
  const short* Bg0 = Bt + (size_t)(bn * 256 + w * 32 + rA) * K + gA;
  const short* Bg1 = Bg0 + (size_t)16 * K;

  // fragment reads: slot = quad ^ swz(lane15)
  const int qs = ((quad ^ ((lane15 & 3) ^ ((lane15 >> 2) & 3))) * 8);

  floatx4 acc[4][4] = {};
  const int nk = K >> 5;
  for (int kb = 0; kb < nk; ++kb) {
    const int k0 = kb * 32;
    async16(Ag + k0, &As[w * 512]);
    async16(Bg0 + k0, &Bs[w * 1024]);
    async16(Bg1 + k0, &Bs[w * 1024 + 512]);
    __syncthreads();
    short8 af[4], bfr[4];
#pragma unroll
    for (int i = 0; i < 4; ++i) {
      af[i]  = *(const short8*)&As[(wm * 64 + i * 16 + lane15) * 32 + qs];
      bfr[i] = *(const short8*)&Bs[(wn * 64 + i * 16 + lane15) * 32 + qs];
    }
#pragma unroll
    for (int i = 0; i < 4; ++i)
#pragma unroll
      for (int j = 0; j < 4; ++j)
        // swapped operands: lane holds C[m=i*16+lane15][n=j*16+quad*4+reg]
        acc[i][j] = __builtin_amdgcn_mfma_f32_16x16x32_bf16(bfr[j], af[i], acc[i][j], 0, 0, 0);
    __syncthreads();
  }

  // ---- pass 1: z = acc + bias (+res) (+gelu); stats for LN ----
  float sum_[4], sq_[4];
#pragma unroll
  for (int i = 0; i < 4; ++i) { sum_[i] = 0.0f; sq_[i] = 0.0f; }
#pragma unroll
  for (int i = 0; i < 4; ++i) {
    size_t rowg = (size_t)bm * 128 + wm * 64 + i * 16 + lane15;
#pragma unroll
    for (int j = 0; j < 4; ++j) {
      int nloc = wn * 64 + j * 16 + quad * 4;
      floatx4 b4 = *(const floatx4*)(bias + bn * 256 + nloc);
      shortx4 r4;
      if (res) r4 = *(const shortx4*)(res + rowg * 256 + nloc);
#pragma unroll
      for (int r = 0; r < 4; ++r) {
        float z = acc[i][j][r] + b4[r];
        if (res) z += bf2f(r4[r]);
        if (act) z = gelu_fast(z);
        acc[i][j][r] = z;
        if (ln) { sum_[i] += z; sq_[i] += z * z; }
      }
    }
  }

  if (ln) {
#pragma unroll
    for (int i = 0; i < 4; ++i) {
      sum_[i] += __shfl_xor(sum_[i], 16); sum_[i] += __shfl_xor(sum_[i], 32);
      sq_[i]  += __shfl_xor(sq_[i], 16);  sq_[i]  += __shfl_xor(sq_[i], 32);
    }
    if (quad == 0) {
#pragma unroll
      for (int i = 0; i < 4; ++i) {
        int lr = wm * 64 + i * 16 + lane15;
        redS[lr * 4 + wn] = sum_[i];
        redS2[lr * 4 + wn] = sq_[i];
      }
    }
    __syncthreads();
#pragma unroll
    for (int i = 0; i < 4; ++i) {
      int lr = wm * 64 + i * 16 + lane15;
      float s = redS[lr * 4] + redS[lr * 4 + 1] + redS[lr * 4 + 2] + redS[lr * 4 + 3];
      float q = redS2[lr * 4] + redS2[lr * 4 + 1] + redS2[lr * 4 + 2] + redS2[lr * 4 + 3];
      float mu = s * (1.0f / 256.0f);
      float var = q * (1.0f / 256.0f) - mu * mu;
      float rs = rsqrtf(var + 1e-5f);
      size_t rowg = (size_t)bm * 128 + wm * 64 + i * 16 + lane15;
#pragma unroll
      for (int j = 0; j < 4; ++j) {
        int nloc = wn * 64 + j * 16 + quad * 4;
        floatx4 y;
#pragma unroll
        for (int r = 0; r < 4; ++r) y[r] = (acc[i][j][r] - mu) * rs;
        acc[i][j] = y;
        if (tot) {
          floatx4* tp = (floatx4*)(tot + rowg * 256 + nloc);
          floatx4 t = *tp;
#pragma unroll
          for (int r = 0; r < 4; ++r) t[r] += y[r];
          *tp = t;
        }
      }
    }
  }

  const int vtrans = (vt != nullptr) && (bn == 2);

  // ---- staged store: 4 chunks of 32 rows x 256 cols (LDS stride 264) ----
#pragma unroll
  for (int i = 0; i < 4; ++i) {
    __syncthreads();
    int lr = wm * 16 + lane15;
#pragma unroll
    for (int j = 0; j < 4; ++j) {
      shortx4 o;
#pragma unroll
      for (int r = 0; r < 4; ++r) o[r] = f2bf(acc[i][j][r]);
      *(shortx4*)&smem[lr * 264 + wn * 64 + j * 16 + quad * 4] = o;
    }
    __syncthreads();
    if (vtrans) {
      // transpose chunk: vt[b][d][s], d = tid&255, 16 consecutive s per thread
      int d = tid & 255;
      int grp = tid >> 8;                          // 0/1 -> token-row group
      short vv[16];
#pragma unroll
      for (int rr = 0; rr < 16; ++rr) vv[rr] = smem[(grp * 16 + rr) * 264 + d];
      size_t row = ((size_t)((bm >> 1) * 256 + d)) * 256 + (bm & 1) * 128 + grp * 64 + i * 16;
      *(short8*)(vt + row) = *(short8*)&vv[0];
      *(short8*)(vt + row + 8) = *(short8*)&vv[8];
    } else {
#pragma unroll
      for (int it = 0; it < 2; ++it) {
        int t2 = tid + it * 512;
        int lr2 = t2 >> 5, c = (t2 & 31) * 8;
        short8 v = *(const short8*)&smem[lr2 * 264 + c];
        size_t rowg = (size_t)bm * 128 + (lr2 >> 4) * 64 + i * 16 + (lr2 & 15);
        short* dst = chunked ? out + (size_t)bn * M * 256 + rowg * 256 + c
                             : out + rowg * (size_t)N + bn * 256 + c;
        *(short8*)dst = v;
      }
    }
  }
}

// ---------------- flash attention: block = (b, h, q-half of 128 rows) ---------------
// K/V^T tiles of 64 keys, double-buffered, XOR-swizzled; online softmax; causal skip.
__global__ __launch_bounds__(256, 4) void attn_kernel(
    const short* __restrict__ qg, const short* __restrict__ kg,
    const short* __restrict__ vtg, const int* __restrict__ ids,
    short* __restrict__ ctxg) {
  __shared__ short lds[20480];   // Kt[2][64][64] | Vt[2][64][64] | Pt[4][16][64]
  const int tid = threadIdx.x, lane = tid & 63, w = tid >> 6;
  const int lane15 = lane & 15, quad = lane >> 4;
  const int l7 = lane15 & 7;
  const int bx = blockIdx.x;
  const int qh = bx & 1, h = (bx >> 1) & 3, b = bx >> 3;
  const int kbmax = qh * 2 + 1;

  // Q fragments (A-layout): m = lane15, k = quad*8+j
  short8 qf[2][2];
#pragma unroll
  for (int t = 0; t < 2; ++t) {
    int q0 = qh * 128 + t * 64 + w * 16;
#pragma unroll
    for (int ks = 0; ks < 2; ++ks)
      qf[t][ks] = *(const short8*)(qg + (size_t)(b * 256 + q0 + lane15) * 256 +
                                   h * 64 + ks * 32 + quad * 8);
  }

  float m_[2][4], l_[2][4];
  floatx4 o[2][4];
#pragma unroll
  for (int t = 0; t < 2; ++t)
#pragma unroll
    for (int r = 0; r < 4; ++r) {
      m_[t][r] = -1e30f; l_[t][r] = 0.0f;
#pragma unroll
      for (int dt = 0; dt < 4; ++dt) o[t][dt][r] = 0.0f;
    }

  // staging (swizzled): wave covers rows srow and srow+32; group = (lane&7)^(row&7)
  const int srow = w * 8 + (lane >> 3);
  const int g8 = ((lane & 7) ^ (srow & 7)) * 8;
  const short* kgp = kg + (size_t)(b * 256 + srow) * 256 + h * 64 + g8;   // + kb*64*256
  const short* vgp = vtg + (size_t)(b * 256 + h * 64 + srow) * 256 + g8;  // + kb*64
  short* pbuf = &lds[16384 + w * 1024];

  // stage tile kb into buffer ib: 2 async16 per wave for K (8KB) and for V (8KB)
#define STAGE_TILE(kb_, ib_)                                                       \
  do {                                                                             \
    async16(kgp + (size_t)(kb_) * 64 * 256,        &lds[(ib_) * 4096 + w * 512]);  \
    async16(kgp + (size_t)((kb_) * 64 + 32) * 256, &lds[(ib_) * 4096 + 2048 + w * 512]); \
    async16(vgp + (kb_) * 64,            &lds[8192 + (ib_) * 4096 + w * 512]);     \
    async16(vgp + 32 * 256 + (kb_) * 64, &lds[8192 + (ib_) * 4096 + 2048 + w * 512]); \
  } while (0)

  STAGE_TILE(0, 0);

  for (int kb = 0; kb <= kbmax; ++kb) {
    __syncthreads();
    if (kb < kbmax) {
      int ib = (kb + 1) & 1;
      STAGE_TILE(kb + 1, ib);
    }
    const short* kbuf = &lds[(kb & 1) * 4096];
    const short* vbuf = &lds[8192 + (kb & 1) * 4096];

    float padb[4];
#pragma unroll
    for (int t16 = 0; t16 < 4; ++t16)
      padb[t16] = (ids[b * 256 + kb * 64 + t16 * 16 + lane15] > 0) ? 0.0f : -10000.0f;

#pragma unroll
    for (int t = 0; t < 2; ++t) {
      if (qh * 2 + t < kb) continue;             // causal: q-subtile entirely masked
      const int q0 = qh * 128 + t * 64 + w * 16;
      const int diag = (qh * 2 + t == kb);
      floatx4 e[4];
#pragma unroll
      for (int t16 = 0; t16 < 4; ++t16) {
        floatx4 a = {0.f, 0.f, 0.f, 0.f};
#pragma unroll
        for (int ks = 0; ks < 2; ++ks) {
          short8 kf = *(const short8*)&kbuf[(t16 * 16 + lane15) * 64 +
                                            (((ks * 4 + quad) ^ l7) * 8)];
          a = __builtin_amdgcn_mfma_f32_16x16x32_bf16(qf[t][ks], kf, a, 0, 0, 0);
        }
        if (diag) {
          int kk = kb * 64 + t16 * 16 + lane15;
#pragma unroll
          for (int r = 0; r < 4; ++r) {
            int q = q0 + quad * 4 + r;
            e[t16][r] = a[r] * 0.125f + ((kk <= q) ? padb[t16] : -10000.0f);
          }
        } else {
#pragma unroll
          for (int r = 0; r < 4; ++r) e[t16][r] = a[r] * 0.125f + padb[t16];
        }
      }
      // online softmax update (reduction over keys = lane15 x t16)
#pragma unroll
      for (int r = 0; r < 4; ++r) {
        float mx = fmaxf(fmaxf(e[0][r], e[1][r]), fmaxf(e[2][r], e[3][r]));
        mx = fmaxf(mx, __shfl_xor(mx, 1));
        mx = fmaxf(mx, __shfl_xor(mx, 2));
        mx = fmaxf(mx, __shfl_xor(mx, 4));
        mx = fmaxf(mx, __shfl_xor(mx, 8));
        float mn = fmaxf(m_[t][r], mx);
        float alpha = __expf(m_[t][r] - mn);
        m_[t][r] = mn;
        float s = 0.0f;
#pragma unroll
        for (int t16 = 0; t16 < 4; ++t16) {
          float ev = __expf(e[t16][r] - mn);
          e[t16][r] = ev;
          s += ev;
        }
        s += __shfl_xor(s, 1); s += __shfl_xor(s, 2);
        s += __shfl_xor(s, 4); s += __shfl_xor(s, 8);
        l_[t][r] = l_[t][r] * alpha + s;
#pragma unroll
        for (int dt = 0; dt < 4; ++dt) o[t][dt][r] *= alpha;
        // P store: slot = (k>>3) ^ (q&7) ^ (q>>2)
        int qloc = quad * 4 + r;
        int swq = (qloc & 7) ^ (qloc >> 2);
#pragma unroll
        for (int t16 = 0; t16 < 4; ++t16) {
          int slot = (t16 * 2 + (lane15 >> 3)) ^ swq;
          pbuf[qloc * 64 + slot * 8 + l7] = f2bf(e[t16][r]);
        }
      }
      // PV: A=P (m=q=lane15, k), B=V^T (n=d=lane15, k)
#pragma unroll
      for (int kb2 = 0; kb2 < 2; ++kb2) {
        short8 pf = *(const short8*)&pbuf[lane15 * 64 +
                      ((((kb2 * 4 + quad) ^ l7 ^ (lane15 >> 2)) * 8))];
#pragma unroll
        for (int dt = 0; dt < 4; ++dt) {
          short8 vf = *(const short8*)&vbuf[(dt * 16 + lane15) * 64 +
                        (((kb2 * 4 + quad) ^ l7) * 8)];
          o[t][dt] = __builtin_amdgcn_mfma_f32_16x16x32_bf16(pf, vf, o[t][dt], 0, 0, 0);
        }
      }
    }
  }

#pragma unroll
  for (int t = 0; t < 2; ++t) {
    const int q0 = qh * 128 + t * 64 + w * 16;
#pragma unroll
    for (int r = 0; r < 4; ++r) {
      float inv = 1.0f / l_[t][r];
      size_t row = (size_t)(b * 256 + q0 + quad * 4 + r) * 256 + h * 64;
#pragma unroll
      for (int dt = 0; dt < 4; ++dt)
        ctxg[row + dt * 16 + lane15] = f2bf(o[t][dt][r] * inv);
    }
  }
}

extern "C" void kernel_launch(void* const* d_in, const int* in_sizes, int n_in,
                              void* d_out, int out_size, void* d_ws, size_t ws_size,
                              hipStream_t stream) {
  const int*   ids  = (const int*)d_in[0];
  const float* item = (const float*)d_in[1];
  const float* pos  = (const float*)d_in[2];
  const float* Wq = (const float*)d_in[3];  const float* bq = (const float*)d_in[4];
  const float* Wk = (const float*)d_in[5];  const float* bk = (const float*)d_in[6];
  const float* Wv = (const float*)d_in[7];  const float* bv = (const float*)d_in[8];
  const float* Wo = (const float*)d_in[9];  const float* bo = (const float*)d_in[10];
  const float* W1 = (const float*)d_in[11]; const float* b1 = (const float*)d_in[12];
  const float* W2 = (const float*)d_in[13]; const float* b2 = (const float*)d_in[14];
  float* out = (float*)d_out;

  const size_t EL = (size_t)BQ * SQ * DQ;   // 16,777,216
  short* qb    = (short*)d_ws;
  short* kb    = qb + EL;
  short* vt    = kb + EL;                   // V^T [b][d][s]
  short* ctxb  = vt + EL;
  short* gb    = qb;                        // [M,1024] aliases q/k/vt/ctx (dead by W1)
  short* xb    = ctxb + EL;
  short* hb    = xb + EL;
  short* WqkvT = hb + EL;                   // [L][3][256][256]
  short* WoT   = WqkvT + 2 * 3 * 65536;     // [L][256][256]
  short* W1T   = WoT + 2 * 65536;           // [L][1024][256]
  short* W2T   = W1T + 2 * 262144;          // [L][256][1024]
  float* bqkv  = (float*)(W2T + 2 * 262144);// [L][768]

  const int M = BQ * SQ;                    // 65536

  wconv_qkv_kernel<<<1536, 256, 0, stream>>>(Wq, Wk, Wv, WqkvT);
  wconv_kernel<<<512, 256, 0, stream>>>(Wo, WoT, 256, 256, 131072);
  wconv_kernel<<<2048, 256, 0, stream>>>(W1, W1T, 256, 1024, 524288);
  wconv_kernel<<<2048, 256, 0, stream>>>(W2, W2T, 1024, 256, 524288);
  bconv_kernel<<<6, 256, 0, stream>>>(bq, bk, bv, bqkv);

  embed_kernel<<<M / 4, 256, 0, stream>>>(ids, item, pos, xb, out);

  for (int l = 0; l < 2; ++l) {
    // fused QKV: N=768 chunked -> qb/kb normal, V chunk transposed into vt
    gemm_kernel<<<dim3(3, M / 128), 512, 0, stream>>>(
        xb, WqkvT + (size_t)l * 3 * 65536, bqkv + l * 768, nullptr, qb, nullptr, vt,
        M, 768, 256, 0, 0, 1);
    attn_kernel<<<BQ * HQ * 2, 256, 0, stream>>>(qb, kb, vt, ids, ctxb);
    // Wo: +res(xb), LN -> hb
    gemm_kernel<<<dim3(1, M / 128), 512, 0, stream>>>(
        ctxb, WoT + (size_t)l * 65536, bo + l * 256, xb, hb, nullptr, nullptr,
        M, 256, 256, 0, 1, 0);
    // W1: gelu -> gb
    gemm_kernel<<<dim3(4, M / 128), 512, 0, stream>>>(
        hb, W1T + (size_t)l * 262144, b1 + l * 1024, nullptr, gb, nullptr, nullptr,
        M, 1024, 256, 1, 0, 0);
    // W2: LN -> xb, tot += y
    gemm_kernel<<<dim3(1, M / 128), 512, 0, stream>>>(
        gb, W2T + (size_t)l * 262144, b2 + l * 256, nullptr, xb, out, nullptr,
        M, 256, 1024, 0, 1, 0);
  }
}

// Round 5
// 812.657 us; speedup vs baseline: 1.0670x; 1.0670x over previous
//
#include <hip/hip_runtime.h>
#include <math.h>

typedef __attribute__((ext_vector_type(8))) short short8;
typedef __attribute__((ext_vector_type(4))) short shortx4;
typedef __attribute__((ext_vector_type(4))) float floatx4;

#define BQ 256
#define SQ 256
#define DQ 256
#define HQ 4

__device__ __forceinline__ short f2bf(float f) {
  union { float f; unsigned u; } c; c.f = f;
  unsigned r = c.u + 0x7fffu + ((c.u >> 16) & 1u);
  return (short)(r >> 16);
}
__device__ __forceinline__ float bf2f(short s) {
  union { unsigned u; float f; } c; c.u = ((unsigned)(unsigned short)s) << 16;
  return c.f;
}
__device__ __forceinline__ float gelu_fast(float x) {
  float t = x * (0.7978845608f + 0.0356774081f * x * x);
  return x / (1.0f + __expf(-2.0f * t));
}
__device__ __forceinline__ void async16(const void* g, void* l) {
  __builtin_amdgcn_global_load_lds(
      (const __attribute__((address_space(1))) void*)g,
      (__attribute__((address_space(3))) void*)l, 16, 0, 0);
}

// ---- unified weight transpose+convert (f32 [K,N] -> bf16 [N,K]) + bias concat ------
__global__ __launch_bounds__(256) void wtrans_kernel(
    const float* __restrict__ Wq, const float* __restrict__ Wk, const float* __restrict__ Wv,
    const float* __restrict__ Wo, const float* __restrict__ W1, const float* __restrict__ W2,
    const float* __restrict__ bq, const float* __restrict__ bk, const float* __restrict__ bv,
    short* __restrict__ WqkvT, short* __restrict__ WoT, short* __restrict__ W1T,
    short* __restrict__ W2T, float* __restrict__ bqkv) {
  const int bid = blockIdx.x, tid = threadIdx.x;
  if (bid >= 384) {                       // bias concat: 6 blocks
    int i = bid - 384;                    // l*3+which
    int l = i / 3, which = i - l * 3;
    const float* src = (which == 0) ? bq : ((which == 1) ? bk : bv);
    bqkv[l * 768 + which * 256 + tid] = src[l * 256 + tid];
    return;
  }
  __shared__ float t[64][65];
  const float* src; short* dst; int K, N, tile;
  if (bid < 96)       { int l = bid / 48, r = bid % 48, which = r / 16; tile = r % 16;
    src = ((which == 0) ? Wq : (which == 1) ? Wk : Wv) + l * 65536;
    dst = WqkvT + (l * 3 + which) * 65536; K = 256; N = 256; }
  else if (bid < 128) { int i = bid - 96, l = i / 16; tile = i % 16;
    src = Wo + l * 65536; dst = WoT + l * 65536; K = 256; N = 256; }
  else if (bid < 256) { int i = bid - 128, l = i / 64; tile = i % 64;
    src = W1 + l * 262144; dst = W1T + l * 262144; K = 256; N = 1024; }
  else                { int i = bid - 256, l = i / 64; tile = i % 64;
    src = W2 + l * 262144; dst = W2T + l * 262144; K = 1024; N = 256; }
  const int ntj = N >> 6;
  const int ti = tile / ntj, tj = tile - ti * ntj;
  {
    int r = tid >> 2, c0 = (tid & 3) * 16;
    const float* sp = src + (size_t)(ti * 64 + r) * N + tj * 64 + c0;
#pragma unroll
    for (int j = 0; j < 4; ++j) {
      floatx4 v = *(const floatx4*)(sp + j * 4);
      t[r][c0 + j * 4 + 0] = v[0]; t[r][c0 + j * 4 + 1] = v[1];
      t[r][c0 + j * 4 + 2] = v[2]; t[r][c0 + j * 4 + 3] = v[3];
    }
  }
  __syncthreads();
  {
    int d = tid & 63, ch = tid >> 6;
    short8 o[2];
#pragma unroll
    for (int j = 0; j < 16; ++j) o[j >> 3][j & 7] = f2bf(t[ch * 16 + j][d]);
    short* dp = dst + (size_t)(tj * 64 + d) * K + ti * 64 + ch * 16;
    *(short8*)dp = o[0];
    *(short8*)(dp + 8) = o[1];
  }
}

// ---------------- embedding + LN; writes xb (bf16) and total (f32) ------------------
__global__ __launch_bounds__(256) void embed_kernel(const int* __restrict__ ids,
    const float* __restrict__ item, const float* __restrict__ pos,
    short* __restrict__ xb, float* __restrict__ tot) {
  const int tid = threadIdx.x, lane = tid & 63, w = tid >> 6;
  const int row = blockIdx.x * 4 + w;
  const int s = row & (SQ - 1);
  const int id = ids[row];
  floatx4 a = *(const floatx4*)(item + (size_t)id * DQ + lane * 4);
  floatx4 p = *(const floatx4*)(pos + (size_t)s * DQ + lane * 4);
  float v[4];
#pragma unroll
  for (int i = 0; i < 4; ++i) v[i] = a[i] + p[i];
  float sm = v[0] + v[1] + v[2] + v[3];
  float ss = v[0]*v[0] + v[1]*v[1] + v[2]*v[2] + v[3]*v[3];
#pragma unroll
  for (int off = 32; off; off >>= 1) { sm += __shfl_xor(sm, off); ss += __shfl_xor(ss, off); }
  float mu = sm * (1.0f / DQ);
  float var = ss * (1.0f / DQ) - mu * mu;
  float rs = rsqrtf(var + 1e-5f);
  shortx4 o; floatx4 y;
#pragma unroll
  for (int i = 0; i < 4; ++i) { y[i] = (v[i] - mu) * rs; o[i] = f2bf(y[i]); }
  *(shortx4*)(xb + (size_t)row * DQ + lane * 4) = o;
  *(floatx4*)(tot + (size_t)row * DQ + lane * 4) = y;
}

// ---------------- bf16 MFMA GEMM, tile 128x256, 512 threads, swizzled LDS -----------
// SMODE 0: out row-major [M,N].  SMODE 1: chunked out + bn==2 transposed into vt.
template <int ACT, int LN, int RES, int TOT, int SMODE>
__global__ __launch_bounds__(512, 4) void gemm_kernel(
    const short* __restrict__ A, const short* __restrict__ Bt,
    const float* __restrict__ bias, const short* __restrict__ res,
    short* __restrict__ out, float* __restrict__ tot, short* __restrict__ vt,
    int M, int N, int K) {
  __shared__ short smem[12288];
  short* As = smem;
  short* Bs = smem + 4096;
  float* redS  = (float*)(smem + 8448);
  float* redS2 = redS + 512;
  const int tid = threadIdx.x, lane = tid & 63, w = tid >> 6;
  const int lane15 = lane & 15, quad = lane >> 4;
  const int wm = w & 1, wn = w >> 1;
  const int bm = blockIdx.y, bn = blockIdx.x;

  const int rA = lane >> 2;
  const int swzA = (rA & 3) ^ ((rA >> 2) & 3);
  const int gA = ((lane & 3) ^ swzA) * 8;
  const short* Ag  = A  + (size_t)(bm * 128 + w * 16 + rA) * K + gA;
  const short* Bg0 = Bt + (size_t)(bn * 256 + w * 32 + rA) * K + gA;
  const short* Bg1 = Bg0 + (size_t)16 * K;
  const int qs = ((quad ^ ((lane15 & 3) ^ ((lane15 >> 2) & 3))) * 8);

  floatx4 acc[4][4] = {};
  const int nk = K >> 5;
  for (int kb = 0; kb < nk; ++kb) {
    const int k0 = kb * 32;
    async16(Ag + k0, &As[w * 512]);
    async16(Bg0 + k0, &Bs[w * 1024]);
    async16(Bg1 + k0, &Bs[w * 1024 + 512]);
    __syncthreads();
    short8 af[4], bfr[4];
#pragma unroll
    for (int i = 0; i < 4; ++i) {
      af[i]  = *(const short8*)&As[(wm * 64 + i * 16 + lane15) * 32 + qs];
      bfr[i] = *(const short8*)&Bs[(wn * 64 + i * 16 + lane15) * 32 + qs];
    }
#pragma unroll
    for (int i = 0; i < 4; ++i)
#pragma unroll
      for (int j = 0; j < 4; ++j)
        acc[i][j] = __builtin_amdgcn_mfma_f32_16x16x32_bf16(bfr[j], af[i], acc[i][j], 0, 0, 0);
    __syncthreads();
  }

  float sum_[4], sq_[4];
#pragma unroll
  for (int i = 0; i < 4; ++i) { sum_[i] = 0.0f; sq_[i] = 0.0f; }
#pragma unroll
  for (int i = 0; i < 4; ++i) {
    size_t rowg = (size_t)bm * 128 + wm * 64 + i * 16 + lane15;
#pragma unroll
    for (int j = 0; j < 4; ++j) {
      int nloc = wn * 64 + j * 16 + quad * 4;
      floatx4 b4 = *(const floatx4*)(bias + bn * 256 + nloc);
      shortx4 r4;
      if (RES) r4 = *(const shortx4*)(res + rowg * 256 + nloc);
#pragma unroll
      for (int r = 0; r < 4; ++r) {
        float z = acc[i][j][r] + b4[r];
        if (RES) z += bf2f(r4[r]);
        if (ACT) z = gelu_fast(z);
        acc[i][j][r] = z;
        if (LN) { sum_[i] += z; sq_[i] += z * z; }
      }
    }
  }

  if (LN) {
#pragma unroll
    for (int i = 0; i < 4; ++i) {
      sum_[i] += __shfl_xor(sum_[i], 16); sum_[i] += __shfl_xor(sum_[i], 32);
      sq_[i]  += __shfl_xor(sq_[i], 16);  sq_[i]  += __shfl_xor(sq_[i], 32);
    }
    if (quad == 0) {
#pragma unroll
      for (int i = 0; i < 4; ++i) {
        int lr = wm * 64 + i * 16 + lane15;
        redS[lr * 4 + wn] = sum_[i];
        redS2[lr * 4 + wn] = sq_[i];
      }
    }
    __syncthreads();
#pragma unroll
    for (int i = 0; i < 4; ++i) {
      int lr = wm * 64 + i * 16 + lane15;
      float s = redS[lr * 4] + redS[lr * 4 + 1] + redS[lr * 4 + 2] + redS[lr * 4 + 3];
      float q = redS2[lr * 4] + redS2[lr * 4 + 1] + redS2[lr * 4 + 2] + redS2[lr * 4 + 3];
      float mu = s * (1.0f / 256.0f);
      float var = q * (1.0f / 256.0f) - mu * mu;
      float rs = rsqrtf(var + 1e-5f);
      size_t rowg = (size_t)bm * 128 + wm * 64 + i * 16 + lane15;
#pragma unroll
      for (int j = 0; j < 4; ++j) {
        int nloc = wn * 64 + j * 16 + quad * 4;
        floatx4 y;
#pragma unroll
        for (int r = 0; r < 4; ++r) y[r] = (acc[i][j][r] - mu) * rs;
        acc[i][j] = y;
        if (TOT) {
          floatx4* tp = (floatx4*)(tot + rowg * 256 + nloc);
          floatx4 t = *tp;
#pragma unroll
          for (int r = 0; r < 4; ++r) t[r] += y[r];
          *tp = t;
        }
      }
    }
  }

#pragma unroll
  for (int i = 0; i < 4; ++i) {
    __syncthreads();
    int lr = wm * 16 + lane15;
#pragma unroll
    for (int j = 0; j < 4; ++j) {
      shortx4 o;
#pragma unroll
      for (int r = 0; r < 4; ++r) o[r] = f2bf(acc[i][j][r]);
      *(shortx4*)&smem[lr * 264 + wn * 64 + j * 16 + quad * 4] = o;
    }
    __syncthreads();
    if (SMODE == 1 && bn == 2) {
      int d = tid & 255;
      int grp = tid >> 8;
      short vv[16];
#pragma unroll
      for (int rr = 0; rr < 16; ++rr) vv[rr] = smem[(grp * 16 + rr) * 264 + d];
      size_t row = ((size_t)((bm >> 1) * 256 + d)) * 256 + (bm & 1) * 128 + grp * 64 + i * 16;
      *(short8*)(vt + row) = *(short8*)&vv[0];
      *(short8*)(vt + row + 8) = *(short8*)&vv[8];
    } else {
#pragma unroll
      for (int it = 0; it < 2; ++it) {
        int t2 = tid + it * 512;
        int lr2 = t2 >> 5, c = (t2 & 31) * 8;
        short8 v = *(const short8*)&smem[lr2 * 264 + c];
        size_t rowg = (size_t)bm * 128 + (lr2 >> 4) * 64 + i * 16 + (lr2 & 15);
        short* dst = (SMODE == 1) ? out + (size_t)bn * M * 256 + rowg * 256 + c
                                  : out + rowg * (size_t)N + bn * 256 + c;
        *(short8*)dst = v;
      }
    }
  }
}

// ---------------- flash attention: block = (b, h), 512 threads, 8 waves -------------
// wave w handles q-subtiles {w, 15-w} (16 rows each); K/V tiles of 64 keys dbuffered.
__global__ __launch_bounds__(512, 4) void attn_kernel(
    const short* __restrict__ qg, const short* __restrict__ kg,
    const short* __restrict__ vtg, const int* __restrict__ ids,
    short* __restrict__ ctxg) {
  __shared__ short lds[25088];   // K[2][64][64] | V[2][64][64]@8192 | P[8][16][64]@16384 | padS@24576
  float* padS = (float*)&lds[24576];
  const int tid = threadIdx.x, lane = tid & 63, w = tid >> 6;
  const int lane15 = lane & 15, quad = lane >> 4, l7 = lane15 & 7;
  const int h = blockIdx.x & 3, b = blockIdx.x >> 2;

  if (tid < 256) padS[tid] = (ids[b * 256 + tid] > 0) ? 0.0f : -10000.0f;

  const int stA[2] = {w, 15 - w};
  short8 qf[2][2];
#pragma unroll
  for (int tt = 0; tt < 2; ++tt) {
    int q0 = stA[tt] * 16;
#pragma unroll
    for (int ks = 0; ks < 2; ++ks)
      qf[tt][ks] = *(const short8*)(qg + (size_t)(b * 256 + q0 + lane15) * 256 +
                                    h * 64 + ks * 32 + quad * 8);
  }

  float m_[2][4], l_[2][4];
  floatx4 o[2][4];
#pragma unroll
  for (int tt = 0; tt < 2; ++tt)
#pragma unroll
    for (int r = 0; r < 4; ++r) {
      m_[tt][r] = -1e30f; l_[tt][r] = 0.0f;
#pragma unroll
      for (int dt = 0; dt < 4; ++dt) o[tt][dt][r] = 0.0f;
    }

  // staging: thread covers row tid>>3 (0..63), 16B group (tid&7)^(row&7)
  const int srow = tid >> 3;
  const int g8 = ((tid & 7) ^ (srow & 7)) * 8;
  const short* kgp = kg + (size_t)(b * 256 + srow) * 256 + h * 64 + g8;   // + kb*64*256
  const short* vgp = vtg + (size_t)(b * 256 + h * 64 + srow) * 256 + g8;  // + kb*64
  short* pbuf = &lds[16384 + w * 1024];

#define STG(kb_, ib_)                                                     \
  do {                                                                    \
    async16(kgp + (size_t)(kb_) * 64 * 256, &lds[(ib_) * 4096 + w * 512]);\
    async16(vgp + (kb_) * 64, &lds[8192 + (ib_) * 4096 + w * 512]);       \
  } while (0)

  STG(0, 0);

  for (int kb = 0; kb < 4; ++kb) {
    __syncthreads();
    if (kb < 3) STG(kb + 1, (kb + 1) & 1);
    const short* kbuf = &lds[(kb & 1) * 4096];
    const short* vbuf = &lds[8192 + (kb & 1) * 4096];

#pragma unroll
    for (int tt = 0; tt < 2; ++tt) {
      const int st = stA[tt];
      if (st < 4 * kb) continue;                 // causally done
      const int q0 = st * 16;
      const int diag = (st >> 2) == kb;
      const int stlo = st & 3;
      floatx4 e[4];
#pragma unroll
      for (int t16 = 0; t16 < 4; ++t16) {
        if (diag && t16 > stlo) {                // fully masked sub-block
          e[t16] = (floatx4){-1e30f, -1e30f, -1e30f, -1e30f};
          continue;
        }
        floatx4 a = {0.f, 0.f, 0.f, 0.f};
#pragma unroll
        for (int ks = 0; ks < 2; ++ks) {
          short8 kf = *(const short8*)&kbuf[(t16 * 16 + lane15) * 64 +
                                            (((ks * 4 + quad) ^ l7) * 8)];
          a = __builtin_amdgcn_mfma_f32_16x16x32_bf16(qf[tt][ks], kf, a, 0, 0, 0);
        }
        float pb = padS[kb * 64 + t16 * 16 + lane15];
        if (diag && t16 == stlo) {
          int kk = kb * 64 + t16 * 16 + lane15;
#pragma unroll
          for (int r = 0; r < 4; ++r)
            e[t16][r] = a[r] * 0.125f + ((kk <= q0 + quad * 4 + r) ? pb : -10000.0f);
        } else {
#pragma unroll
          for (int r = 0; r < 4; ++r) e[t16][r] = a[r] * 0.125f + pb;
        }
      }
      // online softmax over this 64-key tile
#pragma unroll
      for (int r = 0; r < 4; ++r) {
        float mx = fmaxf(fmaxf(e[0][r], e[1][r]), fmaxf(e[2][r], e[3][r]));
        mx = fmaxf(mx, __shfl_xor(mx, 1)); mx = fmaxf(mx, __shfl_xor(mx, 2));
        mx = fmaxf(mx, __shfl_xor(mx, 4)); mx = fmaxf(mx, __shfl_xor(mx, 8));
        float mn = fmaxf(m_[tt][r], mx);
        float alpha = __expf(m_[tt][r] - mn);
        m_[tt][r] = mn;
        float s = 0.0f;
#pragma unroll
        for (int t16 = 0; t16 < 4; ++t16) {
          float ev = __expf(e[t16][r] - mn);
          e[t16][r] = ev; s += ev;
        }
        s += __shfl_xor(s, 1); s += __shfl_xor(s, 2);
        s += __shfl_xor(s, 4); s += __shfl_xor(s, 8);
        l_[tt][r] = l_[tt][r] * alpha + s;
#pragma unroll
        for (int dt = 0; dt < 4; ++dt) o[tt][dt][r] *= alpha;
        int qloc = quad * 4 + r;
        int swq = (qloc & 7) ^ (qloc >> 2);
#pragma unroll
        for (int t16 = 0; t16 < 4; ++t16) {
          int slot = (t16 * 2 + (lane15 >> 3)) ^ swq;
          pbuf[qloc * 64 + slot * 8 + l7] = f2bf(e[t16][r]);
        }
      }
      // PV
#pragma unroll
      for (int kb2 = 0; kb2 < 2; ++kb2) {
        short8 pf = *(const short8*)&pbuf[lane15 * 64 +
                      (((kb2 * 4 + quad) ^ l7 ^ (lane15 >> 2)) * 8)];
#pragma unroll
        for (int dt = 0; dt < 4; ++dt) {
          short8 vf = *(const short8*)&vbuf[(dt * 16 + lane15) * 64 +
                        (((kb2 * 4 + quad) ^ l7) * 8)];
          o[tt][dt] = __builtin_amdgcn_mfma_f32_16x16x32_bf16(pf, vf, o[tt][dt], 0, 0, 0);
        }
      }
    }
  }

  // epilogue: per wave, stage 16x64 out-tile in own pbuf (chunk c = dt^quad), then
  // read back 16B/lane and store full 128B lines.
#pragma unroll
  for (int tt = 0; tt < 2; ++tt) {
    const int q0 = stA[tt] * 16;
#pragma unroll
    for (int r = 0; r < 4; ++r) {
      int qloc = quad * 4 + r;
      float inv = 1.0f / l_[tt][r];
#pragma unroll
      for (int dt = 0; dt < 4; ++dt)
        pbuf[qloc * 64 + ((dt ^ quad) * 16) + lane15] = f2bf(o[tt][dt][r] * inv);
    }
#pragma unroll
    for (int it = 0; it < 2; ++it) {
      int idx = it * 64 + lane;
      int row = idx >> 3, u = idx & 7;
      int d0 = (((u >> 1) ^ (row >> 2)) << 4) + (u & 1) * 8;
      short8 v = *(const short8*)&pbuf[row * 64 + u * 8];
      *(short8*)(ctxg + (size_t)(b * 256 + q0 + row) * 256 + h * 64 + d0) = v;
    }
  }
}

extern "C" void kernel_launch(void* const* d_in, const int* in_sizes, int n_in,
                              void* d_out, int out_size, void* d_ws, size_t ws_size,
                              hipStream_t stream) {
  const int*   ids  = (const int*)d_in[0];
  const float* item = (const float*)d_in[1];
  const float* pos  = (const float*)d_in[2];
  const float* Wq = (const float*)d_in[3];  const float* bq = (const float*)d_in[4];
  const float* Wk = (const float*)d_in[5];  const float* bk = (const float*)d_in[6];
  const float* Wv = (const float*)d_in[7];  const float* bv = (const float*)d_in[8];
  const float* Wo = (const float*)d_in[9];  const float* bo = (const float*)d_in[10];
  const float* W1 = (const float*)d_in[11]; const float* b1 = (const float*)d_in[12];
  const float* W2 = (const float*)d_in[13]; const float* b2 = (const float*)d_in[14];
  float* out = (float*)d_out;

  const size_t EL = (size_t)BQ * SQ * DQ;   // 16,777,216
  short* qb    = (short*)d_ws;
  short* kb_   = qb + EL;
  short* vt    = kb_ + EL;                  // V^T [b][d][s]
  short* ctxb  = vt + EL;
  short* gb    = qb;                        // [M,1024] spans qb..ctxb (dead at W1)
  short* xb    = ctxb + EL;
  short* hb    = xb + EL;
  short* WqkvT = hb + EL;                   // [L][3][256][256]
  short* WoT   = WqkvT + 2 * 3 * 65536;
  short* W1T   = WoT + 2 * 65536;           // [L][1024][256]
  short* W2T   = W1T + 2 * 262144;          // [L][256][1024]
  float* bqkv  = (float*)(W2T + 2 * 262144);

  const int M = BQ * SQ;                    // 65536

  wtrans_kernel<<<390, 256, 0, stream>>>(Wq, Wk, Wv, Wo, W1, W2, bq, bk, bv,
                                         WqkvT, WoT, W1T, W2T, bqkv);
  embed_kernel<<<M / 4, 256, 0, stream>>>(ids, item, pos, xb, out);

  for (int l = 0; l < 2; ++l) {
    gemm_kernel<0, 0, 0, 0, 1><<<dim3(3, M / 128), 512, 0, stream>>>(
        xb, WqkvT + (size_t)l * 3 * 65536, bqkv + l * 768, nullptr, qb, nullptr, vt,
        M, 768, 256);
    attn_kernel<<<BQ * HQ, 512, 0, stream>>>(qb, kb_, vt, ids, ctxb);
    gemm_kernel<0, 1, 1, 0, 0><<<dim3(1, M / 128), 512, 0, stream>>>(
        ctxb, WoT + (size_t)l * 65536, bo + l * 256, xb, hb, nullptr, nullptr,
        M, 256, 256);
    gemm_kernel<1, 0, 0, 0, 0><<<dim3(4, M / 128), 512, 0, stream>>>(
        hb, W1T + (size_t)l * 262144, b1 + l * 1024, nullptr, gb, nullptr, nullptr,
        M, 1024, 256);
    gemm_kernel<0, 1, 0, 1, 0><<<dim3(1, M / 128), 512, 0, stream>>>(
        gb, W2T + (size_t)l * 262144, b2 + l * 256, nullptr, xb, out, nullptr,
        M, 256, 1024);
  }
}